// Round 7
// baseline (299.616 us; speedup 1.0000x reference)
//
#include <hip/hip_runtime.h>

#define IMG 512
#define HW (IMG * IMG)
#define NB 32
#define NIMG 64
#define BAND 16
#define NBAND (IMG / BAND)              // 32
#define NSTG 5                          // fused iterations per launch
#define HALO (2 * NSTG)                 // 10
#define NSTEP ((BAND + 2 * HALO) / 2)   // 18 row-pair steps (before stagger)
#define INF __builtin_inff()

// DPP whole-wave shift-by-1 (CDNA keeps Vega wave_shl/shr DPP controls).
// wave_shr1: lane i gets lane i-1's value; lane 0 gets `ident`.
static __device__ __forceinline__ float dpp_from_prev(float v, float ident) {
    return __int_as_float(__builtin_amdgcn_update_dpp(
        __float_as_int(ident), __float_as_int(v), 0x138, 0xF, 0xF, false));
}
// wave_shl1: lane i gets lane i+1's value; lane 63 gets `ident`.
static __device__ __forceinline__ float dpp_from_next(float v, float ident) {
    return __int_as_float(__builtin_amdgcn_update_dpp(
        __float_as_int(ident), __float_as_int(v), 0x130, 0xF, 0xF, false));
}

// One lane owns 8 contiguous columns: a = cols[8l..8l+3], b = cols[8l+4..8l+7].
struct Row { float4 a, b; };

static __device__ __forceinline__ float min3f(float a, float b, float c) { return fminf(fminf(a, b), c); }
static __device__ __forceinline__ float max3f(float a, float b, float c) { return fmaxf(fmaxf(a, b), c); }

static __device__ __forceinline__ Row splat(float v) {
    Row r;
    r.a = make_float4(v, v, v, v);
    r.b = make_float4(v, v, v, v);
    return r;
}

static __device__ __forceinline__ Row rmin3(const Row& x, const Row& y, const Row& z) {
    Row o;
    const float* px = (const float*)&x;
    const float* py = (const float*)&y;
    const float* pz = (const float*)&z;
    float* po = (float*)&o;
#pragma unroll
    for (int i = 0; i < 8; ++i) po[i] = min3f(px[i], py[i], pz[i]);
    return o;
}

static __device__ __forceinline__ Row rmax3(const Row& x, const Row& y, const Row& z) {
    Row o;
    const float* px = (const float*)&x;
    const float* py = (const float*)&y;
    const float* pz = (const float*)&z;
    float* po = (float*)&o;
#pragma unroll
    for (int i = 0; i < 8; ++i) po[i] = max3f(px[i], py[i], pz[i]);
    return o;
}

// Horizontal 3-min across the 512-wide row. Lane-edge neighbors via DPP
// wave shifts; image edges get +inf identity for free from bound_ctrl.
static __device__ __forceinline__ Row hmin3(const Row& v) {
    float shl = dpp_from_prev(v.b.w, INF);
    float shr = dpp_from_next(v.a.x, INF);
    Row o;
    o.a.x = min3f(shl,   v.a.x, v.a.y);
    o.a.y = min3f(v.a.x, v.a.y, v.a.z);
    o.a.z = min3f(v.a.y, v.a.z, v.a.w);
    o.a.w = min3f(v.a.z, v.a.w, v.b.x);
    o.b.x = min3f(v.a.w, v.b.x, v.b.y);
    o.b.y = min3f(v.b.x, v.b.y, v.b.z);
    o.b.z = min3f(v.b.y, v.b.z, v.b.w);
    o.b.w = min3f(v.b.z, v.b.w, shr);
    return o;
}

static __device__ __forceinline__ Row hmax3(const Row& v) {
    float shl = dpp_from_prev(v.b.w, -INF);
    float shr = dpp_from_next(v.a.x, -INF);
    Row o;
    o.a.x = max3f(shl,   v.a.x, v.a.y);
    o.a.y = max3f(v.a.x, v.a.y, v.a.z);
    o.a.z = max3f(v.a.y, v.a.z, v.a.w);
    o.a.w = max3f(v.a.z, v.a.w, v.b.x);
    o.b.x = max3f(v.a.w, v.b.x, v.b.y);
    o.b.y = max3f(v.b.x, v.b.y, v.b.z);
    o.b.z = max3f(v.b.y, v.b.z, v.b.w);
    o.b.w = max3f(v.b.z, v.b.w, shr);
    return o;
}

// out = relu(x - relu(mp - mn)). For x >= 0 on every consumed output this is
// bit-exactly med3(0, x, x - (mp - mn)). Verified on-harness (absmax 0.0,
// rounds 2-6).
static __device__ __forceinline__ Row relu_out(const Row& x, const Row& mp, const Row& mn) {
    Row o;
    const float* px = (const float*)&x;
    const float* pp = (const float*)&mp;
    const float* pm = (const float*)&mn;
    float* po = (float*)&o;
#pragma unroll
    for (int i = 0; i < 8; ++i) {
        float d = pp[i] - pm[i];
        po[i] = __builtin_amdgcn_fmed3f(0.f, px[i], px[i] - d);
    }
    return o;
}

// Branch-free row load: always issues the load, row index clamped into the
// image. OOB semantics applied at CONSUME time by the caller.
static __device__ __forceinline__ Row load_row_clamped(const float* __restrict__ p,
                                                       int r, int lane) {
    const int rc = min(max(r, 0), IMG - 1);
    const float4* q = (const float4*)(p + (size_t)rc * IMG + lane * 8);
    Row o;
    o.a = q[0];
    o.b = q[1];
    return o;
}

// Row-paired skeletonize stage step (round-0 verified structure).
template <bool EDGE>
static __device__ __forceinline__ void step2(Row (&x)[2], Row (&mn)[2],
                                             Row& in0, Row& in1, int t) {
    Row vmin0 = rmin3(x[0], x[1], in0);      // centered row t-1
    Row vmin1 = rmin3(x[1], in0, in1);       // centered row t
    Row mna = hmin3(vmin0);                  // mn[t-1]
    Row mnb = hmin3(vmin1);                  // mn[t]
    if (EDGE) {
        if ((unsigned)(t - 1) >= IMG) mna = splat(-INF);
        if ((unsigned)t >= IMG) mnb = splat(-INF);
    }
    Row vmax0 = rmax3(mn[0], mn[1], mna);    // centered t-2
    Row vmax1 = rmax3(mn[1], mna, mnb);      // centered t-1
    Row mp0 = hmax3(vmax0);
    Row mp1 = hmax3(vmax1);
    Row out0 = relu_out(x[0], mp0, mn[1]);   // out row t-2
    Row out1 = relu_out(x[1], mp1, mna);     // out row t-1
    if (EDGE) {
        if ((unsigned)(t - 2) >= IMG) out0 = splat(INF);
        if ((unsigned)(t - 1) >= IMG) out1 = splat(INF);
    }
    x[0] = in0;  x[1] = in1;
    mn[0] = mna; mn[1] = mnb;
    in0 = out0;  in1 = out1;
}

// Five fused iterations over one 16-row band with PER-BLOCK PHASE STAGGER.
//
// Channel-camping fix (round-6 post-mortem): without stagger, every block's
// current row is ≡ same phase mod 8 rows (B=band*16, 2-row stepping, images
// 1MB apart), so at each instant ALL 2048 waves hit the same HBM channel
// subset (~2/8 of groups -> effective ~1.4 TB/s, 70%+ stall that extra waves
// can't hide). `stag` = extra even lead-in rows (0..14) rotates each block's
// row phase so the 8 classes cover all phases simultaneously. Correctness:
// output row v depends only on input rows v±10, so lead-in rows only feed
// discarded (v<B) outputs — same induction as the INF-seeded warm-up; band-0
// negative rows keep the EDGE consume-time override.
//
// #pragma unroll 1 is deliberate (full unroll -> scratch spill, round 2).
// All loads branch-free (static vmcnt counts); prefetch issued first.
template <bool EDGE, int MODE>
static __device__ __forceinline__ void run(const float* __restrict__ src,
                                           float* __restrict__ dst,
                                           const float* __restrict__ wp,
                                           int B, int lane, int stag,
                                           float& s_prod, float& s_val) {
    Row x[NSTG][2], mn[NSTG][2];
#pragma unroll
    for (int j = 0; j < NSTG; ++j) {
        x[j][0] = splat(INF);   x[j][1] = splat(INF);
        mn[j][0] = splat(-INF); mn[j][1] = splat(-INF);
    }
    const int t0 = B - HALO - stag;
    const int nstep = NSTEP + (stag >> 1);
    Row pre0 = load_row_clamped(src, t0, lane);
    Row pre1 = load_row_clamped(src, t0 + 1, lane);
#pragma unroll 1
    for (int k = 0; k < nstep; ++k) {
        const int t = t0 + 2 * k;
        const int v = t - HALO;              // final-stage out row pair (v, v+1)
        // 1) issue next-step prefetch — in flight across the 5-stage chain
        Row nxt0 = load_row_clamped(src, t + 2, lane);
        Row nxt1 = load_row_clamped(src, t + 3, lane);
        // 2) weight loads (MODE 1): branch-free, index wrapped into the band
        //    so warm-up steps don't fetch unused rows (vw==v when inband).
        Row w0, w1;
        if (MODE == 1) {
            const int vw = B + ((v - B) & (BAND - 1));
            w0 = load_row_clamped(wp, vw, lane);
            w1 = load_row_clamped(wp, vw + 1, lane);
        }
        // 3) consume previous prefetch
        Row in0 = pre0, in1 = pre1;
        if (EDGE) {
            if ((unsigned)t >= IMG) in0 = splat(INF);
            if ((unsigned)(t + 1) >= IMG) in1 = splat(INF);
        }
#pragma unroll
        for (int j = 0; j < NSTG; ++j)
            step2<EDGE>(x[j], mn[j], in0, in1, t - 2 * j);
        const bool inband = (unsigned)(v - B) < BAND;
        if (inband) {
            if (MODE == 0) {
                float4* q0 = (float4*)(dst + (size_t)v * IMG + lane * 8);
                q0[0] = in0.a; q0[1] = in0.b;
                float4* q1 = (float4*)(dst + (size_t)(v + 1) * IMG + lane * 8);
                q1[0] = in1.a; q1[1] = in1.b;
            } else {
                const float* p0 = (const float*)&in0;
                const float* p1 = (const float*)&in1;
                const float* q0 = (const float*)&w0;
                const float* q1 = (const float*)&w1;
#pragma unroll
                for (int i = 0; i < 8; ++i) {
                    s_prod += p0[i] * q0[i] + p1[i] * q1[i];
                    s_val += p0[i] + p1[i];
                }
            }
        }
        // 4) rotate prefetch
        pre0 = nxt0;
        pre1 = nxt1;
    }
}

// __launch_bounds__(64,1): hipcc budgets VGPR cap = 256/min_waves and spills
// past it ((64,4)->64+spill r2, (64,2)->128+spill r4/r5). Grid sustains only
// 2 waves/SIMD anyway, which any VGPR<=256 permits.
__global__ __launch_bounds__(64, 1) void skel5_a(const float* __restrict__ yp,
                                                 const float* __restrict__ yt,
                                                 float* __restrict__ mid) {
    const int blk = blockIdx.x;
    const int img = blk >> 5, band = blk & (NBAND - 1);
    const float* src = (img < NB) ? yp + (size_t)(2 * img + 1) * HW
                                  : yt + (size_t)(2 * (img - NB) + 1) * HW;
    float* dst = mid + (size_t)img * HW;
    const int lane = threadIdx.x;
    const int B = band * BAND;
    const int stag = ((band + img) & 7) * 2;   // de-phase HBM channel access
    float d0 = 0.f, d1 = 0.f;
    if (band == 0 || band == NBAND - 1) run<true, 0>(src, dst, nullptr, B, lane, stag, d0, d1);
    else                                run<false, 0>(src, dst, nullptr, B, lane, stag, d0, d1);
}

__global__ __launch_bounds__(64, 1) void skel5_b(const float* __restrict__ mid,
                                                 const float* __restrict__ yp,
                                                 const float* __restrict__ yt,
                                                 double* __restrict__ acc) {
    const int blk = blockIdx.x;
    const int img = blk >> 5, band = blk & (NBAND - 1);
    const float* src = mid + (size_t)img * HW;
    // skel(pred) pairs with y_true c1; skel(true) pairs with y_pred c1.
    const float* wp = (img < NB) ? yt + (size_t)(2 * img + 1) * HW
                                 : yp + (size_t)(2 * (img - NB) + 1) * HW;
    const int lane = threadIdx.x;
    const int B = band * BAND;
    const int stag = ((band + img) & 7) * 2;

    float s_prod = 0.f, s_val = 0.f;
    if (band == 0 || band == NBAND - 1) run<true, 1>(src, nullptr, wp, B, lane, stag, s_prod, s_val);
    else                                run<false, 1>(src, nullptr, wp, B, lane, stag, s_prod, s_val);

#pragma unroll
    for (int off = 32; off; off >>= 1) {
        s_prod += __shfl_down(s_prod, off);
        s_val += __shfl_down(s_val, off);
    }
    if (lane == 0) {
        const int base = (img < NB) ? 0 : 2;
        atomicAdd(&acc[base], (double)s_prod);
        atomicAdd(&acc[base + 1], (double)s_val);
    }
}

__global__ void finalize(const double* __restrict__ acc, float* __restrict__ out) {
    double tprec = (acc[0] + 1.0) / (acc[1] + 1.0);
    double tsens = (acc[2] + 1.0) / (acc[3] + 1.0);
    out[0] = (float)(1.0 - 2.0 * (tprec * tsens) / (tprec + tsens));
}

extern "C" void kernel_launch(void* const* d_in, const int* in_sizes, int n_in,
                              void* d_out, int out_size, void* d_ws, size_t ws_size,
                              hipStream_t stream) {
    (void)in_sizes; (void)n_in; (void)out_size; (void)ws_size;
    const float* yp = (const float*)d_in[0];
    const float* yt = (const float*)d_in[1];
    float* out = (float*)d_out;

    // Workspace: intermediate skeleton-after-5-iters (64 MB) | acc (4 doubles)
    float* mid = (float*)d_ws;
    double* acc = (double*)(mid + (size_t)NIMG * HW);

    hipMemsetAsync(acc, 0, 4 * sizeof(double), stream);

    const int grid = NIMG * NBAND;  // 2048 single-wave blocks = 2 waves/SIMD
    skel5_a<<<grid, 64, 0, stream>>>(yp, yt, mid);
    skel5_b<<<grid, 64, 0, stream>>>(mid, yp, yt, acc);
    finalize<<<1, 1, 0, stream>>>(acc, out);
}

// Round 8
// 268.386 us; speedup vs baseline: 1.1164x; 1.1164x over previous
//
#include <hip/hip_runtime.h>

#define IMG 512
#define HW (IMG * IMG)
#define NB 32
#define NIMG 64
#define BAND 32
#define NBAND (IMG / BAND)          // 16 bands per image
#define NSTG 5                      // stages per wave; 2 waves = 10 iterations
#define HALO (2 * NSTG)             // 10 rows per 5-stage group
#define T0OFF 20                    // wave0 starts at B - 20 (full 10-iter halo)
#define NSTEP 36                    // t = B-20 .. B+50 step 2
#define INF __builtin_inff()

// DPP whole-wave shift-by-1 (CDNA keeps Vega wave_shl/shr DPP controls).
static __device__ __forceinline__ float dpp_from_prev(float v, float ident) {
    return __int_as_float(__builtin_amdgcn_update_dpp(
        __float_as_int(ident), __float_as_int(v), 0x138, 0xF, 0xF, false));
}
static __device__ __forceinline__ float dpp_from_next(float v, float ident) {
    return __int_as_float(__builtin_amdgcn_update_dpp(
        __float_as_int(ident), __float_as_int(v), 0x130, 0xF, 0xF, false));
}

// One lane owns 8 contiguous columns: a = cols[8l..8l+3], b = cols[8l+4..8l+7].
struct Row { float4 a, b; };

static __device__ __forceinline__ float min3f(float a, float b, float c) { return fminf(fminf(a, b), c); }
static __device__ __forceinline__ float max3f(float a, float b, float c) { return fmaxf(fmaxf(a, b), c); }

static __device__ __forceinline__ Row splat(float v) {
    Row r;
    r.a = make_float4(v, v, v, v);
    r.b = make_float4(v, v, v, v);
    return r;
}

static __device__ __forceinline__ Row rmin3(const Row& x, const Row& y, const Row& z) {
    Row o;
    const float* px = (const float*)&x;
    const float* py = (const float*)&y;
    const float* pz = (const float*)&z;
    float* po = (float*)&o;
#pragma unroll
    for (int i = 0; i < 8; ++i) po[i] = min3f(px[i], py[i], pz[i]);
    return o;
}

static __device__ __forceinline__ Row rmax3(const Row& x, const Row& y, const Row& z) {
    Row o;
    const float* px = (const float*)&x;
    const float* py = (const float*)&y;
    const float* pz = (const float*)&z;
    float* po = (float*)&o;
#pragma unroll
    for (int i = 0; i < 8; ++i) po[i] = max3f(px[i], py[i], pz[i]);
    return o;
}

static __device__ __forceinline__ Row hmin3(const Row& v) {
    float shl = dpp_from_prev(v.b.w, INF);
    float shr = dpp_from_next(v.a.x, INF);
    Row o;
    o.a.x = min3f(shl,   v.a.x, v.a.y);
    o.a.y = min3f(v.a.x, v.a.y, v.a.z);
    o.a.z = min3f(v.a.y, v.a.z, v.a.w);
    o.a.w = min3f(v.a.z, v.a.w, v.b.x);
    o.b.x = min3f(v.a.w, v.b.x, v.b.y);
    o.b.y = min3f(v.b.x, v.b.y, v.b.z);
    o.b.z = min3f(v.b.y, v.b.z, v.b.w);
    o.b.w = min3f(v.b.z, v.b.w, shr);
    return o;
}

static __device__ __forceinline__ Row hmax3(const Row& v) {
    float shl = dpp_from_prev(v.b.w, -INF);
    float shr = dpp_from_next(v.a.x, -INF);
    Row o;
    o.a.x = max3f(shl,   v.a.x, v.a.y);
    o.a.y = max3f(v.a.x, v.a.y, v.a.z);
    o.a.z = max3f(v.a.y, v.a.z, v.a.w);
    o.a.w = max3f(v.a.z, v.a.w, v.b.x);
    o.b.x = max3f(v.a.w, v.b.x, v.b.y);
    o.b.y = max3f(v.b.x, v.b.y, v.b.z);
    o.b.z = max3f(v.b.y, v.b.z, v.b.w);
    o.b.w = max3f(v.b.z, v.b.w, shr);
    return o;
}

// out = relu(x - relu(mp - mn)) == med3(0, x, x-(mp-mn)) for consumed outputs.
// Verified bit-exact on-harness (absmax 0.0, rounds 2-7).
static __device__ __forceinline__ Row relu_out(const Row& x, const Row& mp, const Row& mn) {
    Row o;
    const float* px = (const float*)&x;
    const float* pp = (const float*)&mp;
    const float* pm = (const float*)&mn;
    float* po = (float*)&o;
#pragma unroll
    for (int i = 0; i < 8; ++i) {
        float d = pp[i] - pm[i];
        po[i] = __builtin_amdgcn_fmed3f(0.f, px[i], px[i] - d);
    }
    return o;
}

// Branch-free row load, index clamped; OOB values overridden at consume time.
static __device__ __forceinline__ Row load_row_clamped(const float* __restrict__ p,
                                                       int r, int lane) {
    const int rc = min(max(r, 0), IMG - 1);
    const float4* q = (const float4*)(p + (size_t)rc * IMG + lane * 8);
    Row o;
    o.a = q[0];
    o.b = q[1];
    return o;
}

// Row-paired skeletonize stage step (round-0 verified structure).
template <bool EDGE>
static __device__ __forceinline__ void step2(Row (&x)[2], Row (&mn)[2],
                                             Row& in0, Row& in1, int t) {
    Row vmin0 = rmin3(x[0], x[1], in0);
    Row vmin1 = rmin3(x[1], in0, in1);
    Row mna = hmin3(vmin0);
    Row mnb = hmin3(vmin1);
    if (EDGE) {
        if ((unsigned)(t - 1) >= IMG) mna = splat(-INF);
        if ((unsigned)t >= IMG) mnb = splat(-INF);
    }
    Row vmax0 = rmax3(mn[0], mn[1], mna);
    Row vmax1 = rmax3(mn[1], mna, mnb);
    Row mp0 = hmax3(vmax0);
    Row mp1 = hmax3(vmax1);
    Row out0 = relu_out(x[0], mp0, mn[1]);
    Row out1 = relu_out(x[1], mp1, mna);
    if (EDGE) {
        if ((unsigned)(t - 2) >= IMG) out0 = splat(INF);
        if ((unsigned)(t - 1) >= IMG) out1 = splat(INF);
    }
    x[0] = in0;  x[1] = in1;
    mn[0] = mna; mn[1] = mnb;
    in0 = out0;  in1 = out1;
}

// Two-wave producer-consumer pipeline: wave0 = iterations 0..4 (src -> LDS
// ring), wave1 = iterations 5..9 (LDS ring -> reduction). Eliminates the
// 64 MB mid write + 64 MB re-read of the two-launch scheme (round-7
// post-mortem: every non-spilling variant pinned at ~1.1 TB/s effective HBM,
// so time ~ bytes; this cuts bytes ~40%).
//
// Register discipline: ONE x/mn state block (20 Rows) serves both roles —
// a thread is either wave0 or wave1 — keeping VGPR at the proven NSTG=5
// level (R4 showed 10-stage-per-wave state spills catastrophically).
//
// Ring hazard audit: step k writes slot k&1 (wave0, pre-barrier), reads it
// (wave1, post-barrier). Wave0's next write to the same slot is at k+2,
// reachable only after barrier k+1, which wave1 reaches only after finishing
// its k-consume -> one barrier per step + double buffer is race-free.
//
// Dependency audit: kept outputs v in [B, B+31] need wave1 inputs
// u in [v-10, v+10] valid; wave0 output u is valid for u >= B-10 (needs src
// [u-10,u+10] consumed; t0 = B-20). Warm-up garbage (incl. NaN from INF
// seeding) reaches discarded outputs only and ages out of the finite
// 2-row/stage state — same induction as the verified single-wave kernel.
template <bool EDGE>
static __device__ __forceinline__ void pipe(const float* __restrict__ src,
                                            const float* __restrict__ wp,
                                            float4 (*ring)[2][128],
                                            int B, int lane, int wid,
                                            float& s_prod, float& s_val) {
    Row x[NSTG][2], mn[NSTG][2];
#pragma unroll
    for (int j = 0; j < NSTG; ++j) {
        x[j][0] = splat(INF);   x[j][1] = splat(INF);
        mn[j][0] = splat(-INF); mn[j][1] = splat(-INF);
    }
    const int t0 = B - T0OFF;
    Row pre0 = splat(0.f), pre1 = splat(0.f);
    if (wid == 0) {
        pre0 = load_row_clamped(src, t0, lane);
        pre1 = load_row_clamped(src, t0 + 1, lane);
    }
#pragma unroll 1
    for (int k = 0; k < NSTEP; ++k) {
        const int t = t0 + 2 * k;
        if (wid == 0) {
            // prefetch next src pair; in flight across the 5-stage chain
            Row nxt0 = load_row_clamped(src, t + 2, lane);
            Row nxt1 = load_row_clamped(src, t + 3, lane);
            Row in0 = pre0, in1 = pre1;
            if (EDGE) {
                if ((unsigned)t >= IMG) in0 = splat(INF);
                if ((unsigned)(t + 1) >= IMG) in1 = splat(INF);
            }
#pragma unroll
            for (int j = 0; j < NSTG; ++j)
                step2<EDGE>(x[j], mn[j], in0, in1, t - 2 * j);
            float4* r0 = &ring[k & 1][0][0];
            r0[lane * 2] = in0.a;
            r0[lane * 2 + 1] = in0.b;
            float4* r1 = &ring[k & 1][1][0];
            r1[lane * 2] = in1.a;
            r1[lane * 2 + 1] = in1.b;
            pre0 = nxt0;
            pre1 = nxt1;
        }
        __syncthreads();
        if (wid == 1) {
            const int u = t - HALO;          // stage-5 input row pair
            const int v = u - HALO;          // final output row pair
            const bool inband = (unsigned)(v - B) < BAND;
            // guarded weight loads (R0-style, empirically fastest), issued
            // before the chain so the 5-stage VALU covers their latency
            Row w0, w1;
            if (inband) {
                const float4* q0 = (const float4*)(wp + (size_t)v * IMG + lane * 8);
                w0.a = q0[0]; w0.b = q0[1];
                const float4* q1 = (const float4*)(wp + (size_t)(v + 1) * IMG + lane * 8);
                w1.a = q1[0]; w1.b = q1[1];
            }
            const float4* r0 = &ring[k & 1][0][0];
            Row in0; in0.a = r0[lane * 2]; in0.b = r0[lane * 2 + 1];
            const float4* r1 = &ring[k & 1][1][0];
            Row in1; in1.a = r1[lane * 2]; in1.b = r1[lane * 2 + 1];
#pragma unroll
            for (int j = 0; j < NSTG; ++j)
                step2<EDGE>(x[j], mn[j], in0, in1, u - 2 * j);
            if (inband) {
                const float* p0 = (const float*)&in0;
                const float* p1 = (const float*)&in1;
                const float* q0 = (const float*)&w0;
                const float* q1 = (const float*)&w1;
#pragma unroll
                for (int i = 0; i < 8; ++i) {
                    s_prod += p0[i] * q0[i] + p1[i] * q1[i];
                    s_val += p0[i] + p1[i];
                }
            }
        }
    }
}

// __launch_bounds__(128,1): VGPR cap 256 (hipcc spills past 256/min_waves —
// rounds 2/4/5). Grid 1024 blocks x 2 waves = 2048 waves = 2 waves/SIMD,
// 4 blocks/CU x 8 KB LDS = 32 KB << 160 KB.
__global__ __launch_bounds__(128, 1) void skel10_pipe(const float* __restrict__ yp,
                                                      const float* __restrict__ yt,
                                                      double* __restrict__ acc) {
    __shared__ float4 ring[2][2][128];   // [slot][row][lane*2+half] = 8 KB
    const int blk = blockIdx.x;
    const int img = blk >> 4, band = blk & (NBAND - 1);
    // skel(pred) pairs with y_true c1; skel(true) pairs with y_pred c1.
    const float* src = (img < NB) ? yp + (size_t)(2 * img + 1) * HW
                                  : yt + (size_t)(2 * (img - NB) + 1) * HW;
    const float* wp = (img < NB) ? yt + (size_t)(2 * img + 1) * HW
                                 : yp + (size_t)(2 * (img - NB) + 1) * HW;
    const int lane = threadIdx.x & 63;
    const int wid = threadIdx.x >> 6;
    const int B = band * BAND;

    float s_prod = 0.f, s_val = 0.f;
    // Kept outputs depend on src rows [B-20, B+51]: only bands 0 and 15
    // touch out-of-image rows there -> EDGE for them; interior bands'
    // OOB-index warm-up work feeds discarded outputs only.
    if (band == 0 || band == NBAND - 1)
        pipe<true>(src, wp, ring, B, lane, wid, s_prod, s_val);
    else
        pipe<false>(src, wp, ring, B, lane, wid, s_prod, s_val);

    if (wid == 1) {
#pragma unroll
        for (int off = 32; off; off >>= 1) {
            s_prod += __shfl_down(s_prod, off);
            s_val += __shfl_down(s_val, off);
        }
        if (lane == 0) {
            const int base = (img < NB) ? 0 : 2;
            atomicAdd(&acc[base], (double)s_prod);
            atomicAdd(&acc[base + 1], (double)s_val);
        }
    }
}

__global__ void finalize(const double* __restrict__ acc, float* __restrict__ out) {
    double tprec = (acc[0] + 1.0) / (acc[1] + 1.0);
    double tsens = (acc[2] + 1.0) / (acc[3] + 1.0);
    out[0] = (float)(1.0 - 2.0 * (tprec * tsens) / (tprec + tsens));
}

extern "C" void kernel_launch(void* const* d_in, const int* in_sizes, int n_in,
                              void* d_out, int out_size, void* d_ws, size_t ws_size,
                              hipStream_t stream) {
    (void)in_sizes; (void)n_in; (void)out_size; (void)ws_size;
    const float* yp = (const float*)d_in[0];
    const float* yt = (const float*)d_in[1];
    float* out = (float*)d_out;

    // Workspace: just the 4 reduction accumulators.
    double* acc = (double*)d_ws;
    hipMemsetAsync(acc, 0, 4 * sizeof(double), stream);

    const int grid = NIMG * NBAND;   // 1024 blocks x 128 threads
    skel10_pipe<<<grid, 128, 0, stream>>>(yp, yt, acc);
    finalize<<<1, 1, 0, stream>>>(acc, out);
}